// Round 7
// baseline (300.615 us; speedup 1.0000x reference)
//
#include <hip/hip_runtime.h>
#include <stdint.h>

typedef unsigned short ushort_t;
// may_alias: these vectors reinterpret ushort/bf16/float storage (TBAA).
typedef __bf16 bfx8 __attribute__((ext_vector_type(8), may_alias));
typedef __bf16 bfx2 __attribute__((ext_vector_type(2), may_alias));
typedef unsigned short usx8 __attribute__((ext_vector_type(8), may_alias));
typedef unsigned int uix2 __attribute__((ext_vector_type(2), may_alias));
typedef unsigned int uix4 __attribute__((ext_vector_type(4), may_alias));
typedef float f32x2 __attribute__((ext_vector_type(2)));
typedef float f32x4 __attribute__((ext_vector_type(4)));
typedef float f32x4m __attribute__((ext_vector_type(4), may_alias));
typedef float f32x16 __attribute__((ext_vector_type(16)));

#define BB 2
#define SS 2048
#define EE 1024
#define HH 16
#define DD 64
#define MM (BB * SS)
#define XN ((size_t)MM * EE)     // x elems (4M)
#define WN ((size_t)EE * EE)     // weight elems (1M)
// SCALE * log2(e) folded into Q: softmax runs in base-2 with NO max subtraction
// (scores ~N(0,1.44^2) in base-2 domain; fp32 exp2 overflow needs >60 sd).
#define QSCALE 0.18033688011112042f

__device__ __forceinline__ unsigned short f2bf(float f) {
  unsigned int u = __builtin_bit_cast(unsigned int, f);
  u += 0x7fffu + ((u >> 16) & 1u);   // round-to-nearest-even (unbiased; round-8)
  return (unsigned short)(u >> 16);
}

__device__ __forceinline__ usx8 cvt8(const float* p) {  // fp32 -> bf16 x8, RTNE
  f32x4m a = *(const f32x4m*)p;
  f32x4m b = *(const f32x4m*)(p + 4);
  usx8 r;
  r[0] = f2bf(a[0]); r[1] = f2bf(a[1]); r[2] = f2bf(a[2]); r[3] = f2bf(a[3]);
  r[4] = f2bf(b[0]); r[5] = f2bf(b[1]); r[6] = f2bf(b[2]); r[7] = f2bf(b[3]);
  return r;
}

// pair of f32 -> packed 2x bf16 dword (compiler emits v_cvt_pk_bf16_f32, RTNE)
__device__ __forceinline__ unsigned int pk2(float lo, float hi) {
  bfx2 t;
  t[0] = (__bf16)lo;
  t[1] = (__bf16)hi;
  return __builtin_bit_cast(unsigned int, t);
}

__device__ __forceinline__ void gl_lds16(const ushort_t* g, ushort_t* l) {
  __builtin_amdgcn_global_load_lds(
      (const __attribute__((address_space(1))) unsigned int*)g,
      (__attribute__((address_space(3))) unsigned int*)l, 16, 0, 0);
}

// fp32 -> bf16 bulk conversion: x | wq | wk | wv -> dst (contiguous regions)
__global__ __launch_bounds__(256)
void cvt_qkv(const float* __restrict__ x, const float* __restrict__ wq,
             const float* __restrict__ wk, const float* __restrict__ wv,
             ushort_t* __restrict__ dst) {
  size_t i8 = ((size_t)blockIdx.x * 256 + threadIdx.x) * 8;
  const float* s;
  size_t off;
  if (i8 < XN)               { s = x;  off = i8; }
  else if (i8 < XN + WN)     { s = wq; off = i8 - XN; }
  else if (i8 < XN + 2 * WN) { s = wk; off = i8 - XN - WN; }
  else                       { s = wv; off = i8 - XN - 2 * WN; }
  *(usx8*)(dst + i8) = cvt8(s + off);
}

__global__ __launch_bounds__(256)
void cvt_one(const float* __restrict__ s, ushort_t* __restrict__ dst) {
  size_t i8 = ((size_t)blockIdx.x * 256 + threadIdx.x) * 8;
  *(usx8*)(dst + i8) = cvt8(s + i8);
}

// Merged Q/K/V projection, ONE launch, flat 768-block grid (3 blocks/CU).
// ROUND-5 VERSION RESTORED (round-6 BK=64+swizzle regressed −5 µs: the
// runtime XOR fragment addressing cost more VALU than the halved barrier
// drains saved; T2 swizzle is outside its regime at 2-phase — m252).
//   bid <256  : Q = x wq^T  [MM][EE], scaled by QSCALE
//   256..511  : K = x wk^T  [MM][EE]
//   512..767  : V^T = wv x^T [EE][MM]  (role swap)
// Body = m97 structure: 128x128 tile, BK=32, 4 waves, 4x4 16x16x32 MFMA,
// global_load_lds width-16 into unpadded 128x32 LDS.
__global__ __launch_bounds__(256)
void gemm_qkv(const ushort_t* __restrict__ xb,
              const ushort_t* __restrict__ wqb, const ushort_t* __restrict__ wkb,
              const ushort_t* __restrict__ wvb,
              ushort_t* __restrict__ Qb, ushort_t* __restrict__ Kb,
              ushort_t* __restrict__ Vtb) {
  __shared__ ushort_t As[128 * 32];
  __shared__ ushort_t Bs[128 * 32];

  const int bid = blockIdx.x;
  const ushort_t *A, *W;
  ushort_t* C;
  int bx, by, N;
  float scale = 1.0f;
  if (bid < 512) {               // Q or K: grid 8 x 32 over [MM][EE]
    int t = bid & 255;
    bx = t & 7;  by = t >> 3;
    A = xb;  N = EE;
    if (bid < 256) { W = wqb; C = Qb; scale = QSCALE; }
    else           { W = wkb; C = Kb; }
  } else {                       // V^T: grid 32 x 8 over [EE][MM]
    int t = bid - 512;
    bx = t & 31; by = t >> 5;
    A = wvb; W = xb; C = Vtb; N = MM;
  }
  const int K = EE;

  const int tid = threadIdx.x;
  const int lane = tid & 63;
  const int w = tid >> 6;
  const int l15 = lane & 15, l16 = lane >> 4;
  const int m0 = by * 128;
  const int n0 = bx * 128;
  const int wr = w >> 1, wc = w & 1;

  f32x4 acc[4][4];
#pragma unroll
  for (int i = 0; i < 4; ++i)
#pragma unroll
    for (int j = 0; j < 4; ++j)
#pragma unroll
      for (int r = 0; r < 4; ++r) acc[i][j][r] = 0.0f;

  for (int k0 = 0; k0 < K; k0 += 32) {
#pragma unroll
    for (int q = 0; q < 2; ++q) {
      int c = w * 128 + q * 64 + lane;
      int row = c >> 2, col = c & 3;
      gl_lds16(A + (size_t)(m0 + row) * K + k0 + col * 8,
               As + (size_t)(w * 128 + q * 64) * 8);
      gl_lds16(W + (size_t)(n0 + row) * K + k0 + col * 8,
               Bs + (size_t)(w * 128 + q * 64) * 8);
    }
    __syncthreads();

    bfx8 af[4], bfr[4];
#pragma unroll
    for (int i = 0; i < 4; ++i) {
      int mr = wr * 64 + i * 16 + l15;
      af[i] = *(const bfx8*)(As + mr * 32 + l16 * 8);
      int nr = wc * 64 + i * 16 + l15;
      bfr[i] = *(const bfx8*)(Bs + nr * 32 + l16 * 8);
    }
#pragma unroll
    for (int i = 0; i < 4; ++i)
#pragma unroll
      for (int j = 0; j < 4; ++j)
        acc[i][j] = __builtin_amdgcn_mfma_f32_16x16x32_bf16(af[i], bfr[j],
                                                            acc[i][j], 0, 0, 0);
    __syncthreads();
  }

  // C/D layout (m91-verified): col = lane&15, row = (lane>>4)*4 + reg
#pragma unroll
  for (int i = 0; i < 4; ++i) {
    int mr = m0 + wr * 64 + i * 16 + l16 * 4;
#pragma unroll
    for (int j = 0; j < 4; ++j) {
      int nc = n0 + wc * 64 + j * 16 + l15;
#pragma unroll
      for (int r = 0; r < 4; ++r)
        C[(size_t)(mr + r) * N + nc] = f2bf(acc[i][j][r] * scale);
    }
  }
}

// O-projection GEMM, fp32 output. ROUND-5 VERSION RESTORED: 64x128 tile
// (grid (8,64) = 512 blocks = 2 blocks/CU), BK=32, no swizzle. LDS 12KB.
__global__ __launch_bounds__(256)
void gemm_o(const ushort_t* __restrict__ A, const ushort_t* __restrict__ W,
            float* __restrict__ C, int M, int N, int K) {
  __shared__ ushort_t As[64 * 32];
  __shared__ ushort_t Bs[128 * 32];

  const int tid = threadIdx.x;
  const int lane = tid & 63;
  const int w = tid >> 6;
  const int l15 = lane & 15, l16 = lane >> 4;
  const int m0 = blockIdx.y * 64;
  const int n0 = blockIdx.x * 128;
  const int wr = w >> 1, wc = w & 1;

  f32x4 acc[2][4];
#pragma unroll
  for (int i = 0; i < 2; ++i)
#pragma unroll
    for (int j = 0; j < 4; ++j)
#pragma unroll
      for (int r = 0; r < 4; ++r) acc[i][j][r] = 0.0f;

  // staging: A-tile 64x32 = 256 16B chunks (1/thread); B-tile 128x32 = 512
  // chunks (2/thread). chunk c: row = c>>2, col8 = c&3.
  const int ca = w * 64 + lane;
  const int ar = ca >> 2, ac = ca & 3;

  for (int k0 = 0; k0 < K; k0 += 32) {
    gl_lds16(A + (size_t)(m0 + ar) * K + k0 + ac * 8,
             As + (size_t)(w * 64) * 8);
#pragma unroll
    for (int q = 0; q < 2; ++q) {
      int c = w * 128 + q * 64 + lane;
      int row = c >> 2, col = c & 3;
      gl_lds16(W + (size_t)(n0 + row) * K + k0 + col * 8,
               Bs + (size_t)(w * 128 + q * 64) * 8);
    }
    __syncthreads();

    bfx8 af[2], bfr[4];
#pragma unroll
    for (int i = 0; i < 2; ++i) {
      int mr = wr * 32 + i * 16 + l15;
      af[i] = *(const bfx8*)(As + mr * 32 + l16 * 8);
    }
#pragma unroll
    for (int j = 0; j < 4; ++j) {
      int nr = wc * 64 + j * 16 + l15;
      bfr[j] = *(const bfx8*)(Bs + nr * 32 + l16 * 8);
    }
#pragma unroll
    for (int i = 0; i < 2; ++i)
#pragma unroll
      for (int j = 0; j < 4; ++j)
        acc[i][j] = __builtin_amdgcn_mfma_f32_16x16x32_bf16(af[i], bfr[j],
                                                            acc[i][j], 0, 0, 0);
    __syncthreads();
  }

#pragma unroll
  for (int i = 0; i < 2; ++i) {
    int mr = m0 + wr * 32 + i * 16 + l16 * 4;
#pragma unroll
    for (int j = 0; j < 4; ++j) {
      int nc = n0 + wc * 64 + j * 16 + l15;
#pragma unroll
      for (int r = 0; r < 4; ++r)
        C[(size_t)(mr + r) * N + nc] = acc[i][j][r];
    }
  }
}

// Flash attention, SPLIT-K x2 (round-4 structure, VGPR fix): 4096 waves
// = 16 waves/CU = 4/SIMD — double round-5's occupancy, with the per-tile
// serial chain halved (KVBLK=32: 8 MFMA + 16 exp2/iter).
// ROUND-4 POST-MORTEM FIX: __launch_bounds__(128) WITHOUT the min-waves
// clamp. (128,4) forced arch-VGPR to 64 and spilled the softmax working
// set (WRITE_SIZE 8.2->12.3MB). Persistent state is ~100 VGPR < 128, so
// natural allocation gives 4 waves/SIMD without spills.
// Fixed-base softmax makes split-K additive: partial O and partial lsum
// from disjoint key ranges just add (no max tracking, no rescale).
// Block = 128 thr = 2 waves, SAME 32 q-rows, wave w handles keys
// [w*1024, w*1024+1024) in 32-key tiles. Each wave's K/V tile is LDS-
// PRIVATE (per-wave DS ops are in-order -> zero barriers in main loop).
// Tiles: Ks [32 key][64 d] stride 72; Vs [64 d][32 key] stride 36
// (conflict-free staging writes + fragment reads; measured 0 conflicts).
// 9.2KB/wave -> 18.4KB/block -> 8 blocks/CU.
// End merge: ONE __syncthreads; wave 0 parks o/lsum in its dead LDS
// region (stride-33 floats = conflict-free), wave 1 adds, normalizes
// by 1/(l0+l1), stores.
// XCD-aware decode (T1): all q-tiles of one (b,h) on one XCD -> K/V
// L2-resident (measured FETCH 69.7 -> 12.3 MB).
// QK^T TRANSPOSED: S^T[key][q] = mfma(K, Q); C/D layout (m74/m101):
// col = lane&31 = q, row = key = (r&3) + 8*(r>>2) + 4*hi. Softmax fully
// in-register (fixed-base exp2, Q pre-scaled by SCALE*log2e). P -> bf16
// PV B-fragments via v_cvt_pk_bf16_f32 + permlane32_swap. PV swapped:
// O^T[d][q] = mfma(V^T-frag, P-frag) -> q stays lane-local.
// s_setprio(1) wraps MFMA clusters (T5). Q and AO alias (Ab=Qb).
__global__ __launch_bounds__(128)
void attn_fwd(const ushort_t* Q, const ushort_t* __restrict__ Kg,
              const ushort_t* __restrict__ Vt_g, ushort_t* AO) {
  // per-wave region: Ks 32*72 = 2304 + Vs 64*36 = 2304 ushorts (9216 B)
  __shared__ ushort_t KV[2 * 4608];

  const int tid = threadIdx.x;
  const int lane = tid & 63;
  const int w = tid >> 6;
  const int l31 = lane & 31, hi = lane >> 5;
  // XCD-aware decode of flat 2048-block grid (8 XCDs round-robin on wgid)
  const int n = blockIdx.x;
  const int xcd = n & 7, rr = n >> 3;
  const int g = xcd * 4 + (rr >> 6);
  const int qt = rr & 63;
  const int h = g & 15, b = g >> 4;
  const int q0 = qt * 32;

  ushort_t* Ks = KV + w * 4608;
  ushort_t* Vs = Ks + 2304;
  const int kOff = w * (SS / 2);   // this wave's key-range start

  const ushort_t* kbase = Kg + (size_t)b * SS * EE + h * DD;          // K[s][d]
  const ushort_t* vbase = Vt_g + (size_t)h * DD * MM + (size_t)b * SS; // Vt[d][s]

  // Q as B-operand fragments: bq[t] = Q[q0+l31][h*64 + t*16 + hi*8 .. +8)
  bfx8 bq[4];
#pragma unroll
  for (int t = 0; t < 4; ++t)
    bq[t] = *(const bfx8*)(Q + (size_t)(b * SS + q0 + l31) * EE + h * DD +
                           t * 16 + hi * 8);

  f32x16 o0, o1;       // O^T accumulators: d 0-31 / 32-63, q = l31
#pragma unroll
  for (int r = 0; r < 16; ++r) { o0[r] = 0.0f; o1[r] = 0.0f; }
  f32x2 ls2;
  ls2[0] = 0.0f; ls2[1] = 0.0f;

  // staging: K tile 32x64 = 256 16B-chunks, chunk c = lane+64i:
  //   row = (lane>>3)+8i, col8 = lane&7  (coalesced 128B row segments)
  // V tile 64x32 = 256 chunks: row = (lane>>2)+16i, col8 = lane&3
  const int kr = lane >> 3, kc = lane & 7;
  const int vr = lane >> 2, vc = lane & 3;

  usx8 kreg[4], vreg[4];
#pragma unroll
  for (int i = 0; i < 4; ++i) {
    kreg[i] = *(const usx8*)(kbase + (size_t)(kOff + kr + 8 * i) * EE + kc * 8);
    vreg[i] = *(const usx8*)(vbase + (size_t)(vr + 16 * i) * MM + kOff + vc * 8);
  }

  for (int kt = 0; kt < SS / 2; kt += 32) {
    // stage current tile (in-order DS: cannot pass last tile's reads)
#pragma unroll
    for (int i = 0; i < 4; ++i) {
      *(usx8*)(Ks + (kr + 8 * i) * 72 + kc * 8) = kreg[i];
      *(usx8*)(Vs + (vr + 16 * i) * 36 + vc * 8) = vreg[i];
    }
    // prefetch next tile; latency hides under this tile's compute
    if (kt + 32 < SS / 2) {
#pragma unroll
      for (int i = 0; i < 4; ++i) {
        kreg[i] = *(const usx8*)(kbase +
                                 (size_t)(kOff + kt + 32 + kr + 8 * i) * EE +
                                 kc * 8);
        vreg[i] = *(const usx8*)(vbase + (size_t)(vr + 16 * i) * MM + kOff +
                                 kt + 32 + vc * 8);
      }
    }

    // QK^T (swapped): pa = S^T[32 keys][q]
    f32x16 pa;
#pragma unroll
    for (int r = 0; r < 16; ++r) pa[r] = 0.0f;
    __builtin_amdgcn_s_setprio(1);
#pragma unroll
    for (int t = 0; t < 4; ++t) {
      bfx8 ak = *(const bfx8*)(Ks + l31 * 72 + t * 16 + hi * 8);
      pa = __builtin_amdgcn_mfma_f32_32x32x16_bf16(ak, bq[t], pa, 0, 0, 0);
    }
    __builtin_amdgcn_s_setprio(0);

    // fixed-base softmax, fully in-register
#pragma unroll
    for (int r = 0; r < 16; ++r) pa[r] = __builtin_exp2f(pa[r]);
#pragma unroll
    for (int s = 0; s < 8; ++s) {
      f32x2 ta;
      ta[0] = pa[2 * s]; ta[1] = pa[2 * s + 1];
      ls2 += ta;
    }

    // P -> bf16 B-fragments: fd[kk] holds P[q=l31][kk*16 + hi*8 + 0..7]
    unsigned int dw[8];
#pragma unroll
    for (int s = 0; s < 8; ++s) dw[s] = pk2(pa[2 * s], pa[2 * s + 1]);
    bfx8 fd[2];
#pragma unroll
    for (int g2 = 0; g2 < 2; ++g2) {
      auto sA = __builtin_amdgcn_permlane32_swap(dw[4 * g2 + 0], dw[4 * g2 + 2],
                                                 false, false);
      auto sB = __builtin_amdgcn_permlane32_swap(dw[4 * g2 + 1], dw[4 * g2 + 3],
                                                 false, false);
      uix4 f;
      f[0] = sA[0]; f[1] = sB[0]; f[2] = sA[1]; f[3] = sB[1];
      fd[g2] = __builtin_bit_cast(bfx8, f);
    }

    // PV (swapped): o[dt] += V^T[d][key] * P[q][key]
    __builtin_amdgcn_s_setprio(1);
#pragma unroll
    for (int kk = 0; kk < 2; ++kk) {
      bfx8 av0 = *(const bfx8*)(Vs + l31 * 36 + kk * 16 + hi * 8);
      bfx8 av1 = *(const bfx8*)(Vs + (32 + l31) * 36 + kk * 16 + hi * 8);
      o0 = __builtin_amdgcn_mfma_f32_32x32x16_bf16(av0, fd[kk], o0, 0, 0, 0);
      o1 = __builtin_amdgcn_mfma_f32_32x32x16_bf16(av1, fd[kk], o1, 0, 0, 0);
    }
    __builtin_amdgcn_s_setprio(0);
  }

  float lsum = ls2[0] + ls2[1];

  // split-K merge: w0 parks partials in its dead LDS region; w1 combines.
  // 64 lanes x 33 floats, stride 33 (== 1 mod 32 -> conflict-free).
  float* mbuf = (float*)KV;   // w0's region (8448 B < 9216 B)
  if (w == 0) {
#pragma unroll
    for (int r = 0; r < 16; ++r) {
      mbuf[lane * 33 + r] = o0[r];
      mbuf[lane * 33 + 16 + r] = o1[r];
    }
    mbuf[lane * 33 + 32] = lsum;
  }
  __syncthreads();
  if (w == 1) {
#pragma unroll
    for (int r = 0; r < 16; ++r) {
      o0[r] += mbuf[lane * 33 + r];
      o1[r] += mbuf[lane * 33 + 16 + r];
    }
    lsum += mbuf[lane * 33 + 32];
    lsum += __shfl_xor(lsum, 32);   // lane pair (hi=0/1) holds same q
    float inv = 1.0f / lsum;

    // O^T reg r -> d = dt*32 + (r&3) + 8*(r>>2) + 4*hi ; q = l31.
    // Regs 4g..4g+3 = 4 consecutive d at base 8g+4hi -> one dwordx2 store.
    ushort_t* orow = AO + (size_t)(b * SS + q0 + l31) * EE + h * DD;
#pragma unroll
    for (int g2 = 0; g2 < 4; ++g2) {
      uix2 s0, s1;
      s0[0] = pk2(o0[4 * g2 + 0] * inv, o0[4 * g2 + 1] * inv);
      s0[1] = pk2(o0[4 * g2 + 2] * inv, o0[4 * g2 + 3] * inv);
      *(uix2*)(orow + 8 * g2 + 4 * hi) = s0;
      s1[0] = pk2(o1[4 * g2 + 0] * inv, o1[4 * g2 + 1] * inv);
      s1[1] = pk2(o1[4 * g2 + 2] * inv, o1[4 * g2 + 3] * inv);
      *(uix2*)(orow + 32 + 8 * g2 + 4 * hi) = s1;
    }
  }
}

extern "C" void kernel_launch(void* const* d_in, const int* in_sizes, int n_in,
                              void* d_out, int out_size, void* d_ws, size_t ws_size,
                              hipStream_t stream) {
  // Inputs: full fp32. Output: fp32. (Settled rounds 0-9.)
  const float* x  = (const float*)d_in[0];
  const float* wq = (const float*)d_in[1];
  const float* wk = (const float*)d_in[2];
  const float* wv = (const float*)d_in[3];
  const float* wo = (const float*)d_in[4];
  float* out = (float*)d_out;

  // ws (24 MB): Qb | Kb | Vtb. Ab aliases Qb (each attn block reads exactly
  // the rectangle it later writes; reads precede writes; disjoint rectangles).
  ushort_t* Qb  = (ushort_t*)d_ws;
  ushort_t* Kb  = Qb + XN;
  ushort_t* Vtb = Kb + XN;
  ushort_t* Ab  = Qb;
  // d_out doubles as bf16 scratch until the final GEMM overwrites it:
  // xb(8MB) | wqb(2MB) | wkb(2MB) | wvb(2MB) = 14MB < 16MB.
  ushort_t* S    = (ushort_t*)d_out;
  ushort_t* xb   = S;
  ushort_t* wqb  = S + XN;
  ushort_t* wkb  = S + XN + WN;
  ushort_t* wvb  = S + XN + 2 * WN;
  ushort_t* wob  = Kb;   // Kb is dead after attn; filled by cvt_one post-attn

  dim3 blk(256);
  // 1) bulk fp32->bf16 conversion (x + 3 weights) into d_out scratch
  cvt_qkv<<<dim3((unsigned)((XN + 3 * WN) / (256 * 8))), blk, 0, stream>>>(
      x, wq, wk, wv, S);
  // 2) merged Q,K,V^T projections — ONE launch, 768 blocks (3/CU)
  gemm_qkv<<<dim3(768), blk, 0, stream>>>(xb, wqb, wkb, wvb, Qb, Kb, Vtb);
  // 3) flash attention (writes Ab = Qb): split-K x2, 2048 two-wave blocks
  attn_fwd<<<dim3(2048), dim3(128), 0, stream>>>(Qb, Kb, Vtb, Ab);
  // 4) convert wo into dead Kb region
  cvt_one<<<dim3((unsigned)(WN / (256 * 8))), blk, 0, stream>>>(wo, wob);
  // 5) output projection -> fp32 d_out (overwrites scratch; full coverage)
  gemm_o<<<dim3(EE / 128, MM / 64), blk, 0, stream>>>(
      Ab, wob, out, MM, EE, EE);
}

// Round 8
// 197.648 us; speedup vs baseline: 1.5210x; 1.5210x over previous
//
#include <hip/hip_runtime.h>
#include <stdint.h>

typedef unsigned short ushort_t;
// may_alias: these vectors reinterpret ushort/bf16/float storage (TBAA).
typedef __bf16 bfx8 __attribute__((ext_vector_type(8), may_alias));
typedef __bf16 bfx2 __attribute__((ext_vector_type(2), may_alias));
typedef unsigned short usx8 __attribute__((ext_vector_type(8), may_alias));
typedef unsigned int uix2 __attribute__((ext_vector_type(2), may_alias));
typedef unsigned int uix4 __attribute__((ext_vector_type(4), may_alias));
typedef float f32x2 __attribute__((ext_vector_type(2)));
typedef float f32x4 __attribute__((ext_vector_type(4)));
typedef float f32x4m __attribute__((ext_vector_type(4), may_alias));
typedef float f32x16 __attribute__((ext_vector_type(16)));

#define BB 2
#define SS 2048
#define EE 1024
#define HH 16
#define DD 64
#define MM (BB * SS)
#define XN ((size_t)MM * EE)     // x elems (4M)
#define WN ((size_t)EE * EE)     // weight elems (1M)
// SCALE * log2(e) folded into Q: softmax runs in base-2 with NO max subtraction
// (scores ~N(0,1.44^2) in base-2 domain; fp32 exp2 overflow needs >60 sd).
#define QSCALE 0.18033688011112042f

__device__ __forceinline__ unsigned short f2bf(float f) {
  unsigned int u = __builtin_bit_cast(unsigned int, f);
  u += 0x7fffu + ((u >> 16) & 1u);   // round-to-nearest-even (unbiased; round-8)
  return (unsigned short)(u >> 16);
}

__device__ __forceinline__ usx8 cvt8(const float* p) {  // fp32 -> bf16 x8, RTNE
  f32x4m a = *(const f32x4m*)p;
  f32x4m b = *(const f32x4m*)(p + 4);
  usx8 r;
  r[0] = f2bf(a[0]); r[1] = f2bf(a[1]); r[2] = f2bf(a[2]); r[3] = f2bf(a[3]);
  r[4] = f2bf(b[0]); r[5] = f2bf(b[1]); r[6] = f2bf(b[2]); r[7] = f2bf(b[3]);
  return r;
}

// pair of f32 -> packed 2x bf16 dword (compiler emits v_cvt_pk_bf16_f32, RTNE)
__device__ __forceinline__ unsigned int pk2(float lo, float hi) {
  bfx2 t;
  t[0] = (__bf16)lo;
  t[1] = (__bf16)hi;
  return __builtin_bit_cast(unsigned int, t);
}

__device__ __forceinline__ void gl_lds16(const ushort_t* g, ushort_t* l) {
  __builtin_amdgcn_global_load_lds(
      (const __attribute__((address_space(1))) unsigned int*)g,
      (__attribute__((address_space(3))) unsigned int*)l, 16, 0, 0);
}

// fp32 -> bf16 bulk conversion: x | wq | wk | wv -> dst (contiguous regions)
__global__ __launch_bounds__(256)
void cvt_qkv(const float* __restrict__ x, const float* __restrict__ wq,
             const float* __restrict__ wk, const float* __restrict__ wv,
             ushort_t* __restrict__ dst) {
  size_t i8 = ((size_t)blockIdx.x * 256 + threadIdx.x) * 8;
  const float* s;
  size_t off;
  if (i8 < XN)               { s = x;  off = i8; }
  else if (i8 < XN + WN)     { s = wq; off = i8 - XN; }
  else if (i8 < XN + 2 * WN) { s = wk; off = i8 - XN - WN; }
  else                       { s = wv; off = i8 - XN - 2 * WN; }
  *(usx8*)(dst + i8) = cvt8(s + off);
}

__global__ __launch_bounds__(256)
void cvt_one(const float* __restrict__ s, ushort_t* __restrict__ dst) {
  size_t i8 = ((size_t)blockIdx.x * 256 + threadIdx.x) * 8;
  *(usx8*)(dst + i8) = cvt8(s + i8);
}

// Merged Q/K/V projection, ONE launch, flat 768-block grid (3 blocks/CU).
// m97 structure: 128x128 tile, BK=32, 4 waves, 4x4 16x16x32 MFMA,
// global_load_lds width-16 into unpadded 128x32 LDS. (Round-5 version;
// round-6 BK=64+swizzle regressed — T2 outside its regime at 2-phase.)
//   bid <256  : Q = x wq^T  [MM][EE], scaled by QSCALE
//   256..511  : K = x wk^T  [MM][EE]
//   512..767  : V^T = wv x^T [EE][MM]  (role swap)
__global__ __launch_bounds__(256)
void gemm_qkv(const ushort_t* __restrict__ xb,
              const ushort_t* __restrict__ wqb, const ushort_t* __restrict__ wkb,
              const ushort_t* __restrict__ wvb,
              ushort_t* __restrict__ Qb, ushort_t* __restrict__ Kb,
              ushort_t* __restrict__ Vtb) {
  __shared__ ushort_t As[128 * 32];
  __shared__ ushort_t Bs[128 * 32];

  const int bid = blockIdx.x;
  const ushort_t *A, *W;
  ushort_t* C;
  int bx, by, N;
  float scale = 1.0f;
  if (bid < 512) {               // Q or K: grid 8 x 32 over [MM][EE]
    int t = bid & 255;
    bx = t & 7;  by = t >> 3;
    A = xb;  N = EE;
    if (bid < 256) { W = wqb; C = Qb; scale = QSCALE; }
    else           { W = wkb; C = Kb; }
  } else {                       // V^T: grid 32 x 8 over [EE][MM]
    int t = bid - 512;
    bx = t & 31; by = t >> 5;
    A = wvb; W = xb; C = Vtb; N = MM;
  }
  const int K = EE;

  const int tid = threadIdx.x;
  const int lane = tid & 63;
  const int w = tid >> 6;
  const int l15 = lane & 15, l16 = lane >> 4;
  const int m0 = by * 128;
  const int n0 = bx * 128;
  const int wr = w >> 1, wc = w & 1;

  f32x4 acc[4][4];
#pragma unroll
  for (int i = 0; i < 4; ++i)
#pragma unroll
    for (int j = 0; j < 4; ++j)
#pragma unroll
      for (int r = 0; r < 4; ++r) acc[i][j][r] = 0.0f;

  for (int k0 = 0; k0 < K; k0 += 32) {
#pragma unroll
    for (int q = 0; q < 2; ++q) {
      int c = w * 128 + q * 64 + lane;
      int row = c >> 2, col = c & 3;
      gl_lds16(A + (size_t)(m0 + row) * K + k0 + col * 8,
               As + (size_t)(w * 128 + q * 64) * 8);
      gl_lds16(W + (size_t)(n0 + row) * K + k0 + col * 8,
               Bs + (size_t)(w * 128 + q * 64) * 8);
    }
    __syncthreads();

    bfx8 af[4], bfr[4];
#pragma unroll
    for (int i = 0; i < 4; ++i) {
      int mr = wr * 64 + i * 16 + l15;
      af[i] = *(const bfx8*)(As + mr * 32 + l16 * 8);
      int nr = wc * 64 + i * 16 + l15;
      bfr[i] = *(const bfx8*)(Bs + nr * 32 + l16 * 8);
    }
#pragma unroll
    for (int i = 0; i < 4; ++i)
#pragma unroll
      for (int j = 0; j < 4; ++j)
        acc[i][j] = __builtin_amdgcn_mfma_f32_16x16x32_bf16(af[i], bfr[j],
                                                            acc[i][j], 0, 0, 0);
    __syncthreads();
  }

  // C/D layout (m91-verified): col = lane&15, row = (lane>>4)*4 + reg
#pragma unroll
  for (int i = 0; i < 4; ++i) {
    int mr = m0 + wr * 64 + i * 16 + l16 * 4;
#pragma unroll
    for (int j = 0; j < 4; ++j) {
      int nc = n0 + wc * 64 + j * 16 + l15;
#pragma unroll
      for (int r = 0; r < 4; ++r)
        C[(size_t)(mr + r) * N + nc] = f2bf(acc[i][j][r] * scale);
    }
  }
}

// O-projection GEMM, fp32 output. 64x128 tile (grid (8,64) = 512 blocks
// = 2 blocks/CU), BK=32. LDS 12KB. (Round-5 version.)
__global__ __launch_bounds__(256)
void gemm_o(const ushort_t* __restrict__ A, const ushort_t* __restrict__ W,
            float* __restrict__ C, int M, int N, int K) {
  __shared__ ushort_t As[64 * 32];
  __shared__ ushort_t Bs[128 * 32];

  const int tid = threadIdx.x;
  const int lane = tid & 63;
  const int w = tid >> 6;
  const int l15 = lane & 15, l16 = lane >> 4;
  const int m0 = blockIdx.y * 64;
  const int n0 = blockIdx.x * 128;
  const int wr = w >> 1, wc = w & 1;

  f32x4 acc[2][4];
#pragma unroll
  for (int i = 0; i < 2; ++i)
#pragma unroll
    for (int j = 0; j < 4; ++j)
#pragma unroll
      for (int r = 0; r < 4; ++r) acc[i][j][r] = 0.0f;

  // staging: A-tile 64x32 = 256 16B chunks (1/thread); B-tile 128x32 = 512
  // chunks (2/thread). chunk c: row = c>>2, col8 = c&3.
  const int ca = w * 64 + lane;
  const int ar = ca >> 2, ac = ca & 3;

  for (int k0 = 0; k0 < K; k0 += 32) {
    gl_lds16(A + (size_t)(m0 + ar) * K + k0 + ac * 8,
             As + (size_t)(w * 64) * 8);
#pragma unroll
    for (int q = 0; q < 2; ++q) {
      int c = w * 128 + q * 64 + lane;
      int row = c >> 2, col = c & 3;
      gl_lds16(W + (size_t)(n0 + row) * K + k0 + col * 8,
               Bs + (size_t)(w * 128 + q * 64) * 8);
    }
    __syncthreads();

    bfx8 af[2], bfr[4];
#pragma unroll
    for (int i = 0; i < 2; ++i) {
      int mr = wr * 32 + i * 16 + l15;
      af[i] = *(const bfx8*)(As + mr * 32 + l16 * 8);
    }
#pragma unroll
    for (int j = 0; j < 4; ++j) {
      int nr = wc * 64 + j * 16 + l15;
      bfr[j] = *(const bfx8*)(Bs + nr * 32 + l16 * 8);
    }
#pragma unroll
    for (int i = 0; i < 2; ++i)
#pragma unroll
      for (int j = 0; j < 4; ++j)
        acc[i][j] = __builtin_amdgcn_mfma_f32_16x16x32_bf16(af[i], bfr[j],
                                                            acc[i][j], 0, 0, 0);
    __syncthreads();
  }

#pragma unroll
  for (int i = 0; i < 2; ++i) {
    int mr = m0 + wr * 32 + i * 16 + l16 * 4;
#pragma unroll
    for (int j = 0; j < 4; ++j) {
      int nc = n0 + wc * 64 + j * 16 + l15;
#pragma unroll
      for (int r = 0; r < 4; ++r)
        C[(size_t)(mr + r) * N + nc] = acc[i][j][r];
    }
  }
}

// Flash attention, 4-WAVE SHARED-TILE blocks (m214-style): 128 q-rows per
// block (4 waves x 32), ONE staged 64-key K/V tile shared by all 4 waves.
// RATIONALE (round-8): L2-traffic floor. Per-wave-private tiles (rounds
// 3-7) re-fetch K/V per 32 q-rows: 2048 waves x 32 tiles x 16KB = 1GB of
// L2 traffic = 30 µs floor at 34.5 TB/s — measured 76 µs. Sharing the
// tile across 4 waves cuts global/L2 traffic 4x (floor ~7.5 µs) and
// divides staging work per wave by 4 (4 loads + 4 ds_writes/thread-tile
// -> 2+2), while per-wave compute (in-reg softmax machinery) unchanged.
// Double-buffered LDS (2 x 18.4KB), async-stage order per tile:
//   issue loads(t+1) -> compute(t) from cur -> ds_write nxt -> barrier
// = ONE barrier per tile (round 1 had two + heavier staging).
// Grid 512 blocks = 2 blocks/CU = 8 waves/CU (same occupancy as round 5:
// isolates the traffic effect). Split-K abandoned (rounds 4/7: VGPR).
// XCD decode (T1): 16 q-blocks x 4 (b,h) per XCD -> K/V L2-resident.
// QK^T TRANSPOSED: S^T[key][q] = mfma(K, Q); C/D layout (m74/m101):
// col = lane&31 = q, row = key = (r&3)+8*(r>>2)+4*hi. Softmax fully
// in-register (fixed-base exp2, Q pre-scaled by SCALE*log2e). P -> bf16
// PV B-fragments via v_cvt_pk_bf16_f32 + permlane32_swap. PV swapped:
// O^T[d][q] = mfma(V^T-frag, P-frag) -> q lane-local for 1/lsum.
// s_setprio(1) wraps MFMA clusters (T5). Q and AO alias (Ab=Qb): each
// block reads exactly the q-rectangle it later writes.
__global__ __launch_bounds__(256)
void attn_fwd(const ushort_t* Q, const ushort_t* __restrict__ Kg,
              const ushort_t* __restrict__ Vt_g, ushort_t* AO) {
  __shared__ ushort_t Ks0[64 * 72];   // [key][d], stride 72 (conflict-free)
  __shared__ ushort_t Vs0[64 * 72];   // [d][key]
  __shared__ ushort_t Ks1[64 * 72];
  __shared__ ushort_t Vs1[64 * 72];

  const int tid = threadIdx.x;
  const int lane = tid & 63;
  const int w = tid >> 6;
  const int l31 = lane & 31, hi = lane >> 5;
  // XCD decode of flat 512-block grid: xcd = n&7 owns 4 (b,h) groups x 16
  // q-blocks (128 q-rows each).
  const int n = blockIdx.x;
  const int xcd = n & 7, rr = n >> 3;          // rr in 0..63
  const int g = xcd * 4 + (rr >> 4);           // (b,h) group 0..31
  const int qt = rr & 15;                      // q-block within (b,h)
  const int h = g & 15, b = g >> 4;
  const int q0 = qt * 128 + w * 32;            // this wave's 32 q-rows

  const ushort_t* kbase = Kg + (size_t)b * SS * EE + h * DD;          // K[s][d]
  const ushort_t* vbase = Vt_g + (size_t)h * DD * MM + (size_t)b * SS; // Vt[d][s]

  // Q as B-operand fragments: bq[t] = Q[q0+l31][h*64 + t*16 + hi*8 .. +8)
  bfx8 bq[4];
#pragma unroll
  for (int t = 0; t < 4; ++t)
    bq[t] = *(const bfx8*)(Q + (size_t)(b * SS + q0 + l31) * EE + h * DD +
                           t * 16 + hi * 8);

  f32x16 o0, o1;       // O^T accumulators: d 0-31 / 32-63, q = l31
#pragma unroll
  for (int r = 0; r < 16; ++r) { o0[r] = 0.0f; o1[r] = 0.0f; }
  f32x2 ls2;
  ls2[0] = 0.0f; ls2[1] = 0.0f;

  // staging split across 256 threads: 64x64 tile = 512 16B chunks per
  // matrix; thread handles chunks tid and tid+256 -> rows r0 and r0+32.
  const int r0 = tid >> 3, c0 = tid & 7;

  usx8 k0r, k1r, v0r, v1r;
  // load tile at key offset key0 into regs (coalesced 128B row segments)
  auto load_t = [&](int key0) {
    k0r = *(const usx8*)(kbase + (size_t)(key0 + r0) * EE + c0 * 8);
    k1r = *(const usx8*)(kbase + (size_t)(key0 + r0 + 32) * EE + c0 * 8);
    v0r = *(const usx8*)(vbase + (size_t)r0 * MM + key0 + c0 * 8);
    v1r = *(const usx8*)(vbase + (size_t)(r0 + 32) * MM + key0 + c0 * 8);
  };
  auto write_t = [&](ushort_t* Ksb, ushort_t* Vsb) {
    *(usx8*)(Ksb + r0 * 72 + c0 * 8) = k0r;
    *(usx8*)(Ksb + (r0 + 32) * 72 + c0 * 8) = k1r;
    *(usx8*)(Vsb + r0 * 72 + c0 * 8) = v0r;
    *(usx8*)(Vsb + (r0 + 32) * 72 + c0 * 8) = v1r;
  };
  // compute one 64-key tile from the given buffers
  auto compute_t = [&](const ushort_t* Ksb, const ushort_t* Vsb) {
    // QK^T (swapped): pa = S^T[keys 0-31][q], pb = S^T[keys 32-63][q]
    f32x16 pa, pb;
#pragma unroll
    for (int r = 0; r < 16; ++r) { pa[r] = 0.0f; pb[r] = 0.0f; }
    __builtin_amdgcn_s_setprio(1);
#pragma unroll
    for (int t = 0; t < 4; ++t) {
      bfx8 ak0 = *(const bfx8*)(Ksb + l31 * 72 + t * 16 + hi * 8);
      bfx8 ak1 = *(const bfx8*)(Ksb + (32 + l31) * 72 + t * 16 + hi * 8);
      pa = __builtin_amdgcn_mfma_f32_32x32x16_bf16(ak0, bq[t], pa, 0, 0, 0);
      pb = __builtin_amdgcn_mfma_f32_32x32x16_bf16(ak1, bq[t], pb, 0, 0, 0);
    }
    __builtin_amdgcn_s_setprio(0);

    // fixed-base softmax, fully in-register; lsum as float2 pairs
#pragma unroll
    for (int r = 0; r < 16; ++r) {
      pa[r] = __builtin_exp2f(pa[r]);
      pb[r] = __builtin_exp2f(pb[r]);
    }
#pragma unroll
    for (int s = 0; s < 8; ++s) {
      f32x2 ta, tb;
      ta[0] = pa[2 * s]; ta[1] = pa[2 * s + 1];
      tb[0] = pb[2 * s]; tb[1] = pb[2 * s + 1];
      ls2 += ta + tb;
    }

    // P -> bf16 B-fragments: fd[kk] holds P[q=l31][kk*16 + hi*8 + 0..7]
    unsigned int dwA[8], dwB[8];
#pragma unroll
    for (int s = 0; s < 8; ++s) {
      dwA[s] = pk2(pa[2 * s], pa[2 * s + 1]);
      dwB[s] = pk2(pb[2 * s], pb[2 * s + 1]);
    }
    bfx8 fd[4];
#pragma unroll
    for (int g2 = 0; g2 < 2; ++g2) {
      auto sA = __builtin_amdgcn_permlane32_swap(dwA[4 * g2 + 0],
                                                 dwA[4 * g2 + 2], false, false);
      auto sB = __builtin_amdgcn_permlane32_swap(dwA[4 * g2 + 1],
                                                 dwA[4 * g2 + 3], false, false);
      uix4 f;
      f[0] = sA[0]; f[1] = sB[0]; f[2] = sA[1]; f[3] = sB[1];
      fd[g2] = __builtin_bit_cast(bfx8, f);
      auto tA = __builtin_amdgcn_permlane32_swap(dwB[4 * g2 + 0],
                                                 dwB[4 * g2 + 2], false, false);
      auto tB = __builtin_amdgcn_permlane32_swap(dwB[4 * g2 + 1],
                                                 dwB[4 * g2 + 3], false, false);
      uix4 f2;
      f2[0] = tA[0]; f2[1] = tB[0]; f2[2] = tA[1]; f2[3] = tB[1];
      fd[2 + g2] = __builtin_bit_cast(bfx8, f2);
    }

    // PV (swapped): o[dt] += V^T[d][key] * P[q][key]
    __builtin_amdgcn_s_setprio(1);
#pragma unroll
    for (int kk = 0; kk < 4; ++kk) {
      bfx8 av0 = *(const bfx8*)(Vsb + l31 * 72 + kk * 16 + hi * 8);
      bfx8 av1 = *(const bfx8*)(Vsb + (32 + l31) * 72 + kk * 16 + hi * 8);
      o0 = __builtin_amdgcn_mfma_f32_32x32x16_bf16(av0, fd[kk], o0, 0, 0, 0);
      o1 = __builtin_amdgcn_mfma_f32_32x32x16_bf16(av1, fd[kk], o1, 0, 0, 0);
    }
    __builtin_amdgcn_s_setprio(0);
  };

  // prologue: stage tile 0 into buf0
  load_t(0);
  write_t(Ks0, Vs0);
  __syncthreads();

  // main loop: 16 double-iterations, 2 tiles each; 1 barrier per tile.
  // Hazard ledger: writes to nxt-buffer occur AFTER the barrier that ended
  // the previous tile's reads of that buffer; reads of cur-buffer precede
  // the barrier that allows its overwrite. Loads for t+1 issue BEFORE
  // compute(t) -> a full tile of compute covers global latency.
  for (int kt = 0; kt < SS; kt += 128) {
    load_t(kt + 64);             // tile t+1 (kt max 1920 -> 1984 < 2048)
    compute_t(Ks0, Vs0);         // tile t
    write_t(Ks1, Vs1);
    __syncthreads();
    if (kt + 128 < SS) load_t(kt + 128);   // tile t+2
    compute_t(Ks1, Vs1);         // tile t+1
    if (kt + 128 < SS) {
      write_t(Ks0, Vs0);
      __syncthreads();
    }
  }

  float lsum = ls2[0] + ls2[1];
  lsum += __shfl_xor(lsum, 32);   // lane pair (hi=0/1) holds same q
  float inv = 1.0f / lsum;

  // O^T reg r -> d = dt*32 + (r&3) + 8*(r>>2) + 4*hi ; q = l31.
  // Regs 4g..4g+3 = 4 consecutive d at base 8g+4hi -> one dwordx2 store.
  ushort_t* orow = AO + (size_t)(b * SS + q0 + l31) * EE + h * DD;
#pragma unroll
  for (int g2 = 0; g2 < 4; ++g2) {
    uix2 s0, s1;
    s0[0] = pk2(o0[4 * g2 + 0] * inv, o0[4 * g2 + 1] * inv);
    s0[1] = pk2(o0[4 * g2 + 2] * inv, o0[4 * g2 + 3] * inv);
    *(uix2*)(orow + 8 * g2 + 4 * hi) = s0;
    s1[0] = pk2(o1[4 * g2 + 0] * inv, o1[4 * g2 + 1] * inv);
    s1[1] = pk2(o1[4 * g2 + 2] * inv, o1[4 * g2 + 3] * inv);
    *(uix2*)(orow + 32 + 8 * g2 + 4 * hi) = s1;
  }
}

extern "C" void kernel_launch(void* const* d_in, const int* in_sizes, int n_in,
                              void* d_out, int out_size, void* d_ws, size_t ws_size,
                              hipStream_t stream) {
  // Inputs: full fp32. Output: fp32. (Settled rounds 0-9.)
  const float* x  = (const float*)d_in[0];
  const float* wq = (const float*)d_in[1];
  const float* wk = (const float*)d_in[2];
  const float* wv = (const float*)d_in[3];
  const float* wo = (const float*)d_in[4];
  float* out = (float*)d_out;

  // ws (24 MB): Qb | Kb | Vtb. Ab aliases Qb (each attn block reads exactly
  // the rectangle it later writes; reads precede writes; disjoint rectangles).
  ushort_t* Qb  = (ushort_t*)d_ws;
  ushort_t* Kb  = Qb + XN;
  ushort_t* Vtb = Kb + XN;
  ushort_t* Ab  = Qb;
  // d_out doubles as bf16 scratch until the final GEMM overwrites it:
  // xb(8MB) | wqb(2MB) | wkb(2MB) | wvb(2MB) = 14MB < 16MB.
  ushort_t* S    = (ushort_t*)d_out;
  ushort_t* xb   = S;
  ushort_t* wqb  = S + XN;
  ushort_t* wkb  = S + XN + WN;
  ushort_t* wvb  = S + XN + 2 * WN;
  ushort_t* wob  = Kb;   // Kb is dead after attn; filled by cvt_one post-attn

  dim3 blk(256);
  // 1) bulk fp32->bf16 conversion (x + 3 weights) into d_out scratch
  cvt_qkv<<<dim3((unsigned)((XN + 3 * WN) / (256 * 8))), blk, 0, stream>>>(
      x, wq, wk, wv, S);
  // 2) merged Q,K,V^T projections — ONE launch, 768 blocks (3/CU)
  gemm_qkv<<<dim3(768), blk, 0, stream>>>(xb, wqb, wkb, wvb, Qb, Kb, Vtb);
  // 3) flash attention (writes Ab = Qb): 512 four-wave shared-tile blocks
  attn_fwd<<<dim3(512), blk, 0, stream>>>(Qb, Kb, Vtb, Ab);
  // 4) convert wo into dead Kb region
  cvt_one<<<dim3((unsigned)(WN / (256 * 8))), blk, 0, stream>>>(wo, wob);
  // 5) output projection -> fp32 d_out (overwrites scratch; full coverage)
  gemm_o<<<dim3(EE / 128, MM / 64), blk, 0, stream>>>(
      Ab, wob, out, MM, EE, EE);
}